// Round 9
// baseline (859.449 us; speedup 1.0000x reference)
//
#include <hip/hip_runtime.h>
#include <hip/hip_bf16.h>

#define B_  32
#define S_  4096
#define H_  1024
#define M_  (B_*S_)          // 131072 rows of enc

typedef __attribute__((ext_vector_type(8))) short bf16x8;
typedef __attribute__((ext_vector_type(4))) float f32x4;

typedef void __attribute__((address_space(3)))* lds_ptr_t;
typedef void __attribute__((address_space(1)))* gbl_ptr_t;

__device__ __forceinline__ unsigned short f2bf(float x) {
    return __builtin_bit_cast(unsigned short, __float2bfloat16(x));
}
__device__ __forceinline__ float tanh_fast(float x) {
    float e = __expf(2.0f * x);
    return 1.0f - 2.0f / (e + 1.0f);
}

// ---------------- Wh fp32 -> bf16 (2 MB, one-time per call) ----------------
__global__ __launch_bounds__(256) void k_cvt_bf16(const float* __restrict__ in,
                                                  unsigned short* __restrict__ out, int n4) {
    int i = blockIdx.x * 256 + threadIdx.x;
    if (i < n4) {
        float4 f = reinterpret_cast<const float4*>(in)[i];
        ushort4 u;
        u.x = f2bf(f.x); u.y = f2bf(f.y); u.z = f2bf(f.z); u.w = f2bf(f.w);
        reinterpret_cast<ushort4*>(out)[i] = u;
    }
}

// ---------------- q_proj[b][o] = sum_k query[b][k] * Ws[o][k] ----------------
__global__ __launch_bounds__(256) void k_qproj(const float* __restrict__ q,
                                               const float* __restrict__ Ws,
                                               float* __restrict__ qp) {
    const int b = blockIdx.y, oc = blockIdx.x, tid = threadIdx.x;
    __shared__ float ql[H_];
    for (int i = tid; i < H_; i += 256) ql[i] = q[b*H_ + i];
    __syncthreads();
    const int o = oc*256 + tid;
    const float4* w = reinterpret_cast<const float4*>(&Ws[(size_t)o * H_]);
    float acc = 0.f;
    #pragma unroll 4
    for (int k4 = 0; k4 < H_/4; ++k4) {
        float4 ww = w[k4];
        acc += ql[k4*4+0]*ww.x + ql[k4*4+1]*ww.y + ql[k4*4+2]*ww.z + ql[k4*4+3]*ww.w;
    }
    qp[b*H_ + o] = acc;
}

// ---------------- fused scores GEMM: 128x128, fp32-A direct, rotated LDS ----------------
// r2's proven structure (4 waves, dbuf, global_load_lds both operands, sync/K-step,
// 3 blocks/CU) with per-row chunk-slot ROTATION: row-major quads keep 64/128B-contiguous
// global segments (coalescing = r2), rotation spreads the fragment ds_read_b128 across
// banks (2-way = free, vs r2's 8-way). A staged as fp32 straight from enc (no cvt_enc
// pass); fp32->bf16 on the read side, frag-by-frag.
// LDS: A 2x16KB (rows of 32 floats, slot s of row r holds float-chunk (s-r)&7),
//      B 2x8KB  (rows of 32 bf16,  slot s of row r holds bf16-chunk (s-(r>>1))&3).
__global__ __launch_bounds__(256) void k_scores_v(const float* __restrict__ enc,
                                                  const unsigned short* __restrict__ whb,
                                                  const float* __restrict__ qp,
                                                  const float* __restrict__ vw,
                                                  float* __restrict__ sp) {
    __shared__ __align__(1024) char As[2][16384];
    __shared__ __align__(1024) char Bs[2][8192];
    __shared__ float sred[2][128];

    const int tid = threadIdx.x;
    const int l   = tid & 63;
    const int w   = tid >> 6;        // wave 0..3
    const int wr  = w >> 1;          // row half (rows wr*64..+63)
    const int wc  = w & 1;           // col half
    const int fr  = l & 15;
    const int fh  = l >> 4;

    const int h  = blockIdx.x;                 // 8192 blocks
    const int L  = (h & 7) * 1024 + (h >> 3);  // XCD-group swizzle (bijective)
    const int bm = L >> 3;
    const int bn = L & 7;
    const int row0 = bm * 128;
    const int col0 = bn * 128;
    const int b = row0 >> 12;

    // ---- A staging: 4 calls/K-step; call i: rows 32i + (tid>>3), 8 slots x 16B/row ----
    // slot tid&7 sources float-chunk ((tid&7) - (tid>>3)) & 7  (rotation, coalescing kept)
    const int arow   = tid >> 3;
    const int achunk = ((tid & 7) - (tid >> 3)) & 7;
    const float* srcA[4];
    #pragma unroll
    for (int i = 0; i < 4; ++i)
        srcA[i] = enc + (size_t)(row0 + i*32 + arow) * H_ + achunk*4;

    // ---- B staging: 2 calls/K-step; call j: rows 64j + (tid>>2), 4 slots x 16B/row ----
    const int brow   = tid >> 2;
    const int bchunk = ((tid & 3) - ((tid >> 3) & 3)) & 3;
    const unsigned short* srcB[2];
    #pragma unroll
    for (int j = 0; j < 2; ++j)
        srcB[j] = whb + (size_t)(col0 + j*64 + brow) * H_ + bchunk*8;

    auto stage = [&](int buf, int kt) {
        #pragma unroll
        for (int i = 0; i < 4; ++i)
            __builtin_amdgcn_global_load_lds((gbl_ptr_t)(srcA[i] + kt*32),
                (lds_ptr_t)(&As[buf][i*4096 + tid*16]), 16, 0, 0);
        #pragma unroll
        for (int j = 0; j < 2; ++j)
            __builtin_amdgcn_global_load_lds((gbl_ptr_t)(srcB[j] + kt*32),
                (lds_ptr_t)(&Bs[buf][j*4096 + tid*16]), 16, 0, 0);
    };

    // ---- invariant read offsets (rotated slots) ----
    // A: byte = (wr*64 + m2*16 + fr)*128 + (((fh*2 + h) + (l&7)) & 7)*16
    const int aOff0 = wr*8192 + fr*128 + (((fh*2 + 0) + (l & 7)) & 7)*16;
    const int aOff1 = wr*8192 + fr*128 + (((fh*2 + 1) + (l & 7)) & 7)*16;
    // B: byte = (wc*64 + n2*16 + fr)*64 + ((fh + (fr>>1)) & 3)*16
    const int bOff  = wc*4096 + fr*64 + ((fh + (fr >> 1)) & 3)*16;

    auto cvt8 = [](f32x4 x, f32x4 y) -> bf16x8 {
        bf16x8 r;
        r[0] = (short)f2bf(x[0]); r[1] = (short)f2bf(x[1]);
        r[2] = (short)f2bf(x[2]); r[3] = (short)f2bf(x[3]);
        r[4] = (short)f2bf(y[0]); r[5] = (short)f2bf(y[1]);
        r[6] = (short)f2bf(y[2]); r[7] = (short)f2bf(y[3]);
        return r;
    };

    f32x4 acc[4][4] = {};

    stage(0, 0);
    __syncthreads();

    for (int kt = 0; kt < 32; ++kt) {
        const int cur = kt & 1, nxt = cur ^ 1;
        if (kt < 31) stage(nxt, kt + 1);

        bf16x8 af[4], ba[4];
        #pragma unroll
        for (int m2 = 0; m2 < 4; ++m2) {
            f32x4 x = *reinterpret_cast<const f32x4*>(&As[cur][aOff0 + m2*2048]);
            f32x4 y = *reinterpret_cast<const f32x4*>(&As[cur][aOff1 + m2*2048]);
            af[m2] = cvt8(x, y);
        }
        #pragma unroll
        for (int n2 = 0; n2 < 4; ++n2)
            ba[n2] = *reinterpret_cast<const bf16x8*>(&Bs[cur][bOff + n2*1024]);

        #pragma unroll
        for (int i = 0; i < 4; ++i)
            #pragma unroll
            for (int j = 0; j < 4; ++j)
                acc[i][j] = __builtin_amdgcn_mfma_f32_16x16x32_bf16(af[i], ba[j], acc[i][j], 0, 0, 0);

        __syncthreads();
    }

    // ---- epilogue: s_partial[row] = sum_c v[c] * tanh(qp[b][c] + x[row][c]) ----
    float vv[4], qq[4];
    #pragma unroll
    for (int j = 0; j < 4; ++j) {
        int c = col0 + wc*64 + j*16 + fr;
        vv[j] = vw[c];
        qq[j] = qp[b*H_ + c];
    }
    #pragma unroll
    for (int i = 0; i < 4; ++i) {
        #pragma unroll
        for (int r = 0; r < 4; ++r) {
            float s = 0.f;
            #pragma unroll
            for (int j = 0; j < 4; ++j)
                s += vv[j] * tanh_fast(qq[j] + acc[i][j][r]);
            s += __shfl_xor(s, 1, 64); s += __shfl_xor(s, 2, 64);
            s += __shfl_xor(s, 4, 64); s += __shfl_xor(s, 8, 64);
            if (fr == 0)
                sred[wc][wr*64 + i*16 + fh*4 + r] = s;
        }
    }
    __syncthreads();
    if (tid < 128)
        sp[(size_t)bn * M_ + row0 + tid] = sred[0][tid] + sred[1][tid];
}

// ---------------- softmax over S per batch (8 partial panels) ----------------
__global__ __launch_bounds__(256) void k_softmax(const float* __restrict__ sp,
                                                 float* __restrict__ attn) {
    const int b = blockIdx.x, tid = threadIdx.x;
    __shared__ float red[4];
    float vals[16];
    float mx = -1e30f;
    #pragma unroll
    for (int i = 0; i < 16; ++i) {
        int s = i*256 + tid;
        float x = 0.f;
        #pragma unroll
        for (int p = 0; p < 8; ++p) x += sp[(size_t)p*M_ + b*S_ + s];
        vals[i] = x;
        mx = fmaxf(mx, x);
    }
    #pragma unroll
    for (int m = 1; m < 64; m <<= 1) mx = fmaxf(mx, __shfl_xor(mx, m, 64));
    if ((tid & 63) == 0) red[tid >> 6] = mx;
    __syncthreads();
    mx = fmaxf(fmaxf(red[0], red[1]), fmaxf(red[2], red[3]));
    float sum = 0.f;
    #pragma unroll
    for (int i = 0; i < 16; ++i) { vals[i] = __expf(vals[i] - mx); sum += vals[i]; }
    #pragma unroll
    for (int m = 1; m < 64; m <<= 1) sum += __shfl_xor(sum, m, 64);
    __syncthreads();
    if ((tid & 63) == 0) red[tid >> 6] = sum;
    __syncthreads();
    sum = red[0] + red[1] + red[2] + red[3];
    float inv = 1.f / sum;
    #pragma unroll
    for (int i = 0; i < 16; ++i) attn[b*S_ + i*256 + tid] = vals[i] * inv;
}

// ---------------- ctx partials, fp32 enc ----------------
__global__ __launch_bounds__(256) void k_ctx_f(const float* __restrict__ attn,
                                               const float* __restrict__ enc,
                                               float* __restrict__ ctxp) {
    const int sc = blockIdx.x;      // 0..15
    const int b  = blockIdx.y;
    const int hh = threadIdx.x * 4;
    float ax = 0.f, ay = 0.f, az = 0.f, aw = 0.f;
    const int s0 = sc * 256;
    #pragma unroll 4
    for (int s = s0; s < s0 + 256; ++s) {
        float a = attn[b*S_ + s];
        float4 e = *reinterpret_cast<const float4*>(&enc[((size_t)b*S_ + s) * H_ + hh]);
        ax += a*e.x; ay += a*e.y; az += a*e.z; aw += a*e.w;
    }
    float4 o; o.x = ax; o.y = ay; o.z = az; o.w = aw;
    *reinterpret_cast<float4*>(&ctxp[((size_t)sc*B_ + b) * H_ + hh]) = o;
}

// ---------------- out[b][o] = tanh(sum_k cat[b][k] * Wout[o][k]) ----------------
__global__ __launch_bounds__(256) void k_out(const float* __restrict__ ctxp,
                                             const float* __restrict__ q,
                                             const float* __restrict__ Wout,
                                             float* __restrict__ out) {
    const int oc = blockIdx.x, b = blockIdx.y, tid = threadIdx.x;
    __shared__ float cat[2*H_];
    for (int k = tid; k < H_; k += 256) {
        float s = 0.f;
        #pragma unroll
        for (int p = 0; p < 16; ++p) s += ctxp[((size_t)p*B_ + b) * H_ + k];
        cat[k] = s;
        cat[H_ + k] = q[b*H_ + k];
    }
    __syncthreads();
    const int o = oc*256 + tid;
    const float4* w = reinterpret_cast<const float4*>(&Wout[(size_t)o * 2*H_]);
    float acc = 0.f;
    #pragma unroll 4
    for (int k4 = 0; k4 < 2*H_/4; ++k4) {
        float4 ww = w[k4];
        acc += cat[k4*4+0]*ww.x + cat[k4*4+1]*ww.y + cat[k4*4+2]*ww.z + cat[k4*4+3]*ww.w;
    }
    out[b*H_ + o] = tanh_fast(acc);
}

extern "C" void kernel_launch(void* const* d_in, const int* in_sizes, int n_in,
                              void* d_out, int out_size, void* d_ws, size_t ws_size,
                              hipStream_t stream) {
    const float* query = (const float*)d_in[0];
    const float* enc   = (const float*)d_in[1];
    // d_in[2] = src_lengths (int64) — dead in the reference, faithfully unused
    const float* Ws    = (const float*)d_in[3];
    const float* Wh    = (const float*)d_in[4];
    const float* vw    = (const float*)d_in[5];
    const float* Wout  = (const float*)d_in[6];
    float* out = (float*)d_out;

    char* ws = (char*)d_ws;
    unsigned short* whb = (unsigned short*)ws;                 // [1024][1024] bf16, 2 MiB
    float* sp   = (float*)(ws + (2u  << 20));                  // [8][M] 4 MiB
    float* attn = (float*)(ws + (6u  << 20));                  // 512 KiB
    float* qp   = (float*)(ws + (6u  << 20) + (512u << 10));   // 128 KiB
    float* ctxp = (float*)(ws + (7u  << 20));                  // [16][32][1024] 2 MiB
    // total ws footprint: 9 MiB; every buffer fully written before read each call

    k_cvt_bf16<<<dim3(1024),   dim3(256), 0, stream>>>(Wh, whb, H_*H_/4);
    k_qproj   <<<dim3(4, 32),  dim3(256), 0, stream>>>(query, Ws, qp);
    k_scores_v<<<dim3(8192),   dim3(256), 0, stream>>>(enc, whb, qp, vw, sp);
    k_softmax <<<dim3(32),     dim3(256), 0, stream>>>(sp, attn);
    k_ctx_f   <<<dim3(16, 32), dim3(256), 0, stream>>>(attn, enc, ctxp);
    k_out     <<<dim3(4, 32),  dim3(256), 0, stream>>>(ctxp, query, Wout, out);
}

// Round 10
// 694.934 us; speedup vs baseline: 1.2367x; 1.2367x over previous
//
#include <hip/hip_runtime.h>
#include <hip/hip_bf16.h>

#define B_  32
#define S_  4096
#define H_  1024
#define M_  (B_*S_)          // 131072 rows of enc

typedef __attribute__((ext_vector_type(8))) short bf16x8;
typedef __attribute__((ext_vector_type(4))) float f32x4;
typedef __attribute__((ext_vector_type(8))) unsigned short ushort8;

typedef void __attribute__((address_space(3)))* lds_ptr_t;
typedef void __attribute__((address_space(1)))* gbl_ptr_t;

__device__ __forceinline__ unsigned short f2bf(float x) {
    return __builtin_bit_cast(unsigned short, __float2bfloat16(x));
}
__device__ __forceinline__ float bf2f(unsigned short u) {
    return __builtin_bit_cast(float, (unsigned)u << 16);
}
__device__ __forceinline__ float tanh_fast(float x) {
    float e = __expf(2.0f * x);
    return 1.0f - 2.0f / (e + 1.0f);
}

// ---------------- fp32 -> bf16 converters ----------------
__global__ __launch_bounds__(256) void k_cvt_bf16(const float* __restrict__ in,
                                                  unsigned short* __restrict__ out, int n4) {
    int i = blockIdx.x * 256 + threadIdx.x;
    if (i < n4) {
        float4 f = reinterpret_cast<const float4*>(in)[i];
        ushort4 u;
        u.x = f2bf(f.x); u.y = f2bf(f.y); u.z = f2bf(f.z); u.w = f2bf(f.w);
        reinterpret_cast<ushort4*>(out)[i] = u;
    }
}

__global__ __launch_bounds__(256) void k_cvt_enc(const float* __restrict__ in,
                                                 unsigned short* __restrict__ out, int n8) {
    const int stride = gridDim.x * 256;
    for (int i = blockIdx.x * 256 + threadIdx.x; i < n8; i += stride) {
        float4 a = reinterpret_cast<const float4*>(in)[(size_t)i * 2];
        float4 b = reinterpret_cast<const float4*>(in)[(size_t)i * 2 + 1];
        ushort8 u;
        u[0] = f2bf(a.x); u[1] = f2bf(a.y); u[2] = f2bf(a.z); u[3] = f2bf(a.w);
        u[4] = f2bf(b.x); u[5] = f2bf(b.y); u[6] = f2bf(b.z); u[7] = f2bf(b.w);
        reinterpret_cast<ushort8*>(out)[i] = u;
    }
}

// ---------------- q_proj[b][o] = sum_k query[b][k] * Ws[o][k] ----------------
__global__ __launch_bounds__(256) void k_qproj(const float* __restrict__ q,
                                               const float* __restrict__ Ws,
                                               float* __restrict__ qp) {
    const int b = blockIdx.y, oc = blockIdx.x, tid = threadIdx.x;
    __shared__ float ql[H_];
    for (int i = tid; i < H_; i += 256) ql[i] = q[b*H_ + i];
    __syncthreads();
    const int o = oc*256 + tid;
    const float4* w = reinterpret_cast<const float4*>(&Ws[(size_t)o * H_]);
    float acc = 0.f;
    #pragma unroll 4
    for (int k4 = 0; k4 < H_/4; ++k4) {
        float4 ww = w[k4];
        acc += ql[k4*4+0]*ww.x + ql[k4*4+1]*ww.y + ql[k4*4+2]*ww.z + ql[k4*4+3]*ww.w;
    }
    qp[b*H_ + o] = acc;
}

// ---------------- fused scores GEMM: r2 structure + slot-XOR involution swizzle ----------------
// 128x128 tile, 4 waves, dbuf LDS, global_load_lds both operands, sync/K-step, ~4 blocks/CU.
// Subtile = 16 rows x 32 bf16 = 64 slots of 16B (slot s = 4*row + chunk).
// Involution sigma(s) = s ^ ((s>>3)&7): LDS slot t (linear tid*16 dest) holds global slot
// sigma(t); read of global slot g is at LDS slot sigma(g). Per lane-quad the source stays
// one contiguous 64B row-segment (coalescing = r2); per 8/16-lane group the read's bank
// quads are distinct/2-way (conflict-free).
__global__ __launch_bounds__(256) void k_scores_b(const unsigned short* __restrict__ encb,
                                                  const unsigned short* __restrict__ whb,
                                                  const float* __restrict__ qp,
                                                  const float* __restrict__ vw,
                                                  float* __restrict__ sp) {
    __shared__ __align__(1024) char As[2][8192];   // 8 subtiles x 1024B per buf
    __shared__ __align__(1024) char Bs[2][8192];
    __shared__ float sred[2][128];

    const int tid  = threadIdx.x;
    const int l    = tid & 63;
    const int w    = tid >> 6;       // wave 0..3
    const int wr   = w >> 1;         // row half (rows wr*64..+63)
    const int wc   = w & 1;          // col half
    const int fr   = l & 15;
    const int fh   = l >> 4;

    const int h  = blockIdx.x;                 // 8192 blocks
    const int L  = (h & 7) * 1024 + (h >> 3);  // XCD-group swizzle (bijective)
    const int bm = L >> 3;
    const int bn = L & 7;
    const int row0 = bm * 128;
    const int col0 = bn * 128;
    const int b = row0 >> 12;

    // ---- staging source (inverse-swizzled): thread tid, subtile tid>>6 within instr,
    //      slot t = tid&63 -> source slot sigma(t): row sigma>>2, chunk sigma&3 ----
    const int t_    = tid & 63;
    const int sig   = t_ ^ ((t_ >> 3) & 7);
    const int s_sub = tid >> 6;                // subtile within instruction
    const int s_row = sig >> 2;
    const int s_ch  = (sig & 3) * 8;           // bf16 elements
    const unsigned short* gA0 = encb + (size_t)(row0 + s_sub*16 + s_row) * H_ + s_ch;
    const unsigned short* gA1 = gA0 + (size_t)64 * H_;   // subtiles 4..7
    const unsigned short* gB0 = whb  + (size_t)(col0 + s_sub*16 + s_row) * H_ + s_ch;
    const unsigned short* gB1 = gB0 + (size_t)64 * H_;

    auto stage = [&](int buf, int kt) {
        char* la = &As[buf][tid*16];
        char* lb = &Bs[buf][tid*16];
        __builtin_amdgcn_global_load_lds((gbl_ptr_t)(gA0 + kt*32), (lds_ptr_t)la,          16, 0, 0);
        __builtin_amdgcn_global_load_lds((gbl_ptr_t)(gA1 + kt*32), (lds_ptr_t)(la + 4096), 16, 0, 0);
        __builtin_amdgcn_global_load_lds((gbl_ptr_t)(gB0 + kt*32), (lds_ptr_t)lb,          16, 0, 0);
        __builtin_amdgcn_global_load_lds((gbl_ptr_t)(gB1 + kt*32), (lds_ptr_t)(lb + 4096), 16, 0, 0);
    };

    // ---- read offset (swizzled): global slot g = 4*fr + fh -> LDS slot sigma(g) ----
    const int g_   = 4*fr + fh;
    const int rOff = (g_ ^ ((g_ >> 3) & 7)) * 16;   // == (4fr+fh) ^ ((fr>>1)&7), *16

    f32x4 acc[4][4] = {};

    stage(0, 0);
    __syncthreads();

    for (int kt = 0; kt < 32; ++kt) {
        const int cur = kt & 1, nxt = cur ^ 1;
        if (kt < 31) stage(nxt, kt + 1);

        bf16x8 af[4], bfr[4];
        #pragma unroll
        for (int i = 0; i < 4; ++i) {
            af[i]  = *reinterpret_cast<const bf16x8*>(&As[cur][(wr*4 + i)*1024 + rOff]);
            bfr[i] = *reinterpret_cast<const bf16x8*>(&Bs[cur][(wc*4 + i)*1024 + rOff]);
        }
        #pragma unroll
        for (int i = 0; i < 4; ++i)
            #pragma unroll
            for (int j = 0; j < 4; ++j)
                acc[i][j] = __builtin_amdgcn_mfma_f32_16x16x32_bf16(af[i], bfr[j], acc[i][j], 0, 0, 0);

        __syncthreads();
    }

    // epilogue: s_partial[row] = sum_c v[c] * tanh(qp[b][c] + x[row][c])
    float vv[4], qq[4];
    #pragma unroll
    for (int j = 0; j < 4; ++j) {
        int c = col0 + wc*64 + j*16 + fr;
        vv[j] = vw[c];
        qq[j] = qp[b*H_ + c];
    }
    #pragma unroll
    for (int i = 0; i < 4; ++i) {
        #pragma unroll
        for (int r = 0; r < 4; ++r) {
            float s = 0.f;
            #pragma unroll
            for (int j = 0; j < 4; ++j)
                s += vv[j] * tanh_fast(qq[j] + acc[i][j][r]);
            s += __shfl_xor(s, 1, 64); s += __shfl_xor(s, 2, 64);
            s += __shfl_xor(s, 4, 64); s += __shfl_xor(s, 8, 64);
            if (fr == 0)
                sred[wc][wr*64 + i*16 + fh*4 + r] = s;
        }
    }
    __syncthreads();
    if (tid < 128)
        sp[(size_t)bn * M_ + row0 + tid] = sred[0][tid] + sred[1][tid];
}

// ---------------- fused scores GEMM, fp32 A in-flight (fallback, 128^2) ----------------
__global__ __launch_bounds__(256) void k_scores_f(const float* __restrict__ enc,
                                                  const unsigned short* __restrict__ whb,
                                                  const float* __restrict__ qp,
                                                  const float* __restrict__ vw,
                                                  float* __restrict__ sp) {
    __shared__ __align__(16) unsigned short As[2][128][32];
    __shared__ __align__(16) unsigned short Bs[2][128][32];
    __shared__ float sred[2][128];

    const int tid  = threadIdx.x;
    const int lane = tid & 63;
    const int wid  = tid >> 6;
    const int wr = wid >> 1, wc = wid & 1;
    const int fr = lane & 15;
    const int fk = (lane >> 4) * 8;

    const int h  = blockIdx.x;
    const int L  = (h & 7) * 1024 + (h >> 3);
    const int bm = L >> 3;
    const int bn = L & 7;
    const int row0 = bm * 128;
    const int col0 = bn * 128;
    const int b = row0 >> 12;

    const int ar = tid >> 3;
    const int ak = (tid & 7) * 4;
    const int bnr = tid >> 2;
    const int bkk = (tid & 3) * 8;

    float4 areg[4];
    auto loadA = [&](int kt) {
        #pragma unroll
        for (int p = 0; p < 4; ++p)
            areg[p] = *reinterpret_cast<const float4*>(
                &enc[(size_t)(row0 + p*32 + ar) * H_ + kt*32 + ak]);
    };
    auto writeA = [&](int buf) {
        #pragma unroll
        for (int p = 0; p < 4; ++p) {
            ushort4 u;
            u.x = f2bf(areg[p].x); u.y = f2bf(areg[p].y);
            u.z = f2bf(areg[p].z); u.w = f2bf(areg[p].w);
            *reinterpret_cast<ushort4*>(&As[buf][p*32 + ar][ak]) = u;
        }
    };
    auto stageB = [&](int buf, int kt) {
        const unsigned short* g0 = whb + (size_t)(col0 + bnr) * H_ + kt*32 + bkk;
        const unsigned short* g1 = g0 + (size_t)64 * H_;
        char* l0 = (char*)(&Bs[buf][0][0]) + tid*16;
        __builtin_amdgcn_global_load_lds((gbl_ptr_t)g0, (lds_ptr_t)l0,        16, 0, 0);
        __builtin_amdgcn_global_load_lds((gbl_ptr_t)g1, (lds_ptr_t)(l0+4096), 16, 0, 0);
    };

    f32x4 acc[4][4] = {};

    loadA(0);
    stageB(0, 0);
    writeA(0);
    __syncthreads();

    for (int kt = 0; kt < 32; ++kt) {
        const int cur = kt & 1, nxt = cur ^ 1;
        if (kt < 31) { stageB(nxt, kt + 1); loadA(kt + 1); }

        bf16x8 af[4], bfr[4];
        #pragma unroll
        for (int i = 0; i < 4; ++i) {
            af[i]  = *reinterpret_cast<const bf16x8*>(&As[cur][wr*64 + i*16 + fr][fk]);
            bfr[i] = *reinterpret_cast<const bf16x8*>(&Bs[cur][wc*64 + i*16 + fr][fk]);
        }
        #pragma unroll
        for (int i = 0; i < 4; ++i)
            #pragma unroll
            for (int j = 0; j < 4; ++j)
                acc[i][j] = __builtin_amdgcn_mfma_f32_16x16x32_bf16(af[i], bfr[j], acc[i][j], 0, 0, 0);

        if (kt < 31) writeA(nxt);
        __syncthreads();
    }

    float vv[4], qq[4];
    #pragma unroll
    for (int j = 0; j < 4; ++j) {
        int c = col0 + wc*64 + j*16 + fr;
        vv[j] = vw[c];
        qq[j] = qp[b*H_ + c];
    }
    #pragma unroll
    for (int i = 0; i < 4; ++i) {
        #pragma unroll
        for (int r = 0; r < 4; ++r) {
            float s = 0.f;
            #pragma unroll
            for (int j = 0; j < 4; ++j)
                s += vv[j] * tanh_fast(qq[j] + acc[i][j][r]);
            #pragma unroll
            for (int m = 1; m < 16; m <<= 1)
                s += __shfl_xor(s, m, 64);
            if (fr == 0)
                sred[wc][wr*64 + i*16 + (lane >> 4)*4 + r] = s;
        }
    }
    __syncthreads();
    if (tid < 128)
        sp[(size_t)bn * M_ + row0 + tid] = sred[0][tid] + sred[1][tid];
}

// ---------------- softmax over S per batch (P partial panels) ----------------
__global__ __launch_bounds__(256) void k_softmax(const float* __restrict__ sp,
                                                 float* __restrict__ attn, int P) {
    const int b = blockIdx.x, tid = threadIdx.x;
    __shared__ float red[4];
    float vals[16];
    float mx = -1e30f;
    #pragma unroll
    for (int i = 0; i < 16; ++i) {
        int s = i*256 + tid;
        float x = 0.f;
        for (int p = 0; p < P; ++p) x += sp[(size_t)p*M_ + b*S_ + s];
        vals[i] = x;
        mx = fmaxf(mx, x);
    }
    #pragma unroll
    for (int m = 1; m < 64; m <<= 1) mx = fmaxf(mx, __shfl_xor(mx, m, 64));
    if ((tid & 63) == 0) red[tid >> 6] = mx;
    __syncthreads();
    mx = fmaxf(fmaxf(red[0], red[1]), fmaxf(red[2], red[3]));
    float sum = 0.f;
    #pragma unroll
    for (int i = 0; i < 16; ++i) { vals[i] = __expf(vals[i] - mx); sum += vals[i]; }
    #pragma unroll
    for (int m = 1; m < 64; m <<= 1) sum += __shfl_xor(sum, m, 64);
    __syncthreads();
    if ((tid & 63) == 0) red[tid >> 6] = sum;
    __syncthreads();
    sum = red[0] + red[1] + red[2] + red[3];
    float inv = 1.f / sum;
    #pragma unroll
    for (int i = 0; i < 16; ++i) attn[b*S_ + i*256 + tid] = vals[i] * inv;
}

// ---------------- ctx partials, bf16 enc ----------------
__global__ __launch_bounds__(256) void k_ctx_b(const float* __restrict__ attn,
                                               const unsigned short* __restrict__ encb,
                                               float* __restrict__ ctxp) {
    const int sc = blockIdx.x;      // 0..15
    const int b  = blockIdx.y;
    const int hh = threadIdx.x * 4;
    float ax = 0.f, ay = 0.f, az = 0.f, aw = 0.f;
    const int s0 = sc * 256;
    #pragma unroll 4
    for (int s = s0; s < s0 + 256; ++s) {
        float a = attn[b*S_ + s];
        ushort4 e = *reinterpret_cast<const ushort4*>(&encb[((size_t)b*S_ + s) * H_ + hh]);
        ax += a*bf2f(e.x); ay += a*bf2f(e.y); az += a*bf2f(e.z); aw += a*bf2f(e.w);
    }
    float4 o; o.x = ax; o.y = ay; o.z = az; o.w = aw;
    *reinterpret_cast<float4*>(&ctxp[((size_t)sc*B_ + b) * H_ + hh]) = o;
}

// ---------------- ctx partials, fp32 enc (fallback) ----------------
__global__ __launch_bounds__(256) void k_ctx_f(const float* __restrict__ attn,
                                               const float* __restrict__ enc,
                                               float* __restrict__ ctxp) {
    const int sc = blockIdx.x;
    const int b  = blockIdx.y;
    const int hh = threadIdx.x * 4;
    float ax = 0.f, ay = 0.f, az = 0.f, aw = 0.f;
    const int s0 = sc * 256;
    #pragma unroll 4
    for (int s = s0; s < s0 + 256; ++s) {
        float a = attn[b*S_ + s];
        float4 e = *reinterpret_cast<const float4*>(&enc[((size_t)b*S_ + s) * H_ + hh]);
        ax += a*e.x; ay += a*e.y; az += a*e.z; aw += a*e.w;
    }
    float4 o; o.x = ax; o.y = ay; o.z = az; o.w = aw;
    *reinterpret_cast<float4*>(&ctxp[((size_t)sc*B_ + b) * H_ + hh]) = o;
}

// ---------------- out[b][o] = tanh(sum_k cat[b][k] * Wout[o][k]) ----------------
__global__ __launch_bounds__(256) void k_out(const float* __restrict__ ctxp,
                                             const float* __restrict__ q,
                                             const float* __restrict__ Wout,
                                             float* __restrict__ out) {
    const int oc = blockIdx.x, b = blockIdx.y, tid = threadIdx.x;
    __shared__ float cat[2*H_];
    for (int k = tid; k < H_; k += 256) {
        float s = 0.f;
        #pragma unroll
        for (int p = 0; p < 16; ++p) s += ctxp[((size_t)p*B_ + b) * H_ + k];
        cat[k] = s;
        cat[H_ + k] = q[b*H_ + k];
    }
    __syncthreads();
    const int o = oc*256 + tid;
    const float4* w = reinterpret_cast<const float4*>(&Wout[(size_t)o * 2*H_]);
    float acc = 0.f;
    #pragma unroll 4
    for (int k4 = 0; k4 < 2*H_/4; ++k4) {
        float4 ww = w[k4];
        acc += cat[k4*4+0]*ww.x + cat[k4*4+1]*ww.y + cat[k4*4+2]*ww.z + cat[k4*4+3]*ww.w;
    }
    out[b*H_ + o] = tanh_fast(acc);
}

extern "C" void kernel_launch(void* const* d_in, const int* in_sizes, int n_in,
                              void* d_out, int out_size, void* d_ws, size_t ws_size,
                              hipStream_t stream) {
    const float* query = (const float*)d_in[0];
    const float* enc   = (const float*)d_in[1];
    // d_in[2] = src_lengths (int64) — dead in the reference, faithfully unused
    const float* Ws    = (const float*)d_in[3];
    const float* Wh    = (const float*)d_in[4];
    const float* vw    = (const float*)d_in[5];
    const float* Wout  = (const float*)d_in[6];
    float* out = (float*)d_out;

    char* ws = (char*)d_ws;

    if (ws_size >= (266ull << 20)) {
        unsigned short* encb = (unsigned short*)ws;                        // 256 MiB
        unsigned short* whb  = (unsigned short*)(ws + (256ull << 20));     // 2 MiB
        float* sp   = (float*)(ws + (258ull << 20));                       // [8][M] 4 MiB
        float* attn = (float*)(ws + (262ull << 20));                       // 512 KiB
        float* qp   = (float*)(ws + (262ull << 20) + (512u << 10));        // 128 KiB
        float* ctxp = (float*)(ws + (263ull << 20));                       // 2 MiB

        k_cvt_enc <<<dim3(2048),    dim3(256), 0, stream>>>(enc, encb, M_*H_/8);
        k_cvt_bf16<<<dim3(1024),    dim3(256), 0, stream>>>(Wh, whb, H_*H_/4);
        k_qproj   <<<dim3(4, 32),   dim3(256), 0, stream>>>(query, Ws, qp);
        k_scores_b<<<dim3(8192),    dim3(256), 0, stream>>>(encb, whb, qp, vw, sp);
        k_softmax <<<dim3(32),      dim3(256), 0, stream>>>(sp, attn, 8);
        k_ctx_b   <<<dim3(16, 32),  dim3(256), 0, stream>>>(attn, encb, ctxp);
        k_out     <<<dim3(4, 32),   dim3(256), 0, stream>>>(ctxp, query, Wout, out);
    } else {
        unsigned short* whb = (unsigned short*)ws;
        float* sp   = (float*)(ws + (2u  << 20));
        float* attn = (float*)(ws + (6u  << 20));
        float* qp   = (float*)(ws + (6u  << 20) + (512u << 10));
        float* ctxp = (float*)(ws + (7u  << 20));

        k_cvt_bf16<<<dim3(1024),    dim3(256), 0, stream>>>(Wh, whb, H_*H_/4);
        k_qproj   <<<dim3(4, 32),   dim3(256), 0, stream>>>(query, Ws, qp);
        k_scores_f<<<dim3(8192),    dim3(256), 0, stream>>>(enc, whb, qp, vw, sp);
        k_softmax <<<dim3(32),      dim3(256), 0, stream>>>(sp, attn, 8);
        k_ctx_f   <<<dim3(16, 32),  dim3(256), 0, stream>>>(attn, enc, ctxp);
        k_out     <<<dim3(4, 32),   dim3(256), 0, stream>>>(ctxp, query, Wout, out);
    }
}

// Round 11
// 675.472 us; speedup vs baseline: 1.2724x; 1.0288x over previous
//
#include <hip/hip_runtime.h>
#include <hip/hip_bf16.h>

#define B_  32
#define S_  4096
#define H_  1024
#define M_  (B_*S_)          // 131072 rows of enc

typedef __attribute__((ext_vector_type(8))) short bf16x8;
typedef __attribute__((ext_vector_type(4))) float f32x4;
typedef __attribute__((ext_vector_type(8))) unsigned short ushort8;

typedef void __attribute__((address_space(3)))* lds_ptr_t;
typedef void __attribute__((address_space(1)))* gbl_ptr_t;

__device__ __forceinline__ unsigned short f2bf(float x) {
    return __builtin_bit_cast(unsigned short, __float2bfloat16(x));
}
__device__ __forceinline__ float bf2f(unsigned short u) {
    return __builtin_bit_cast(float, (unsigned)u << 16);
}
__device__ __forceinline__ float tanh_fast(float x) {
    float e = __expf(2.0f * x);
    return 1.0f - 2.0f / (e + 1.0f);
}

// ---------------- fp32 -> bf16 converters ----------------
__global__ __launch_bounds__(256) void k_cvt_bf16(const float* __restrict__ in,
                                                  unsigned short* __restrict__ out, int n4) {
    int i = blockIdx.x * 256 + threadIdx.x;
    if (i < n4) {
        float4 f = reinterpret_cast<const float4*>(in)[i];
        ushort4 u;
        u.x = f2bf(f.x); u.y = f2bf(f.y); u.z = f2bf(f.z); u.w = f2bf(f.w);
        reinterpret_cast<ushort4*>(out)[i] = u;
    }
}

__global__ __launch_bounds__(256) void k_cvt_enc(const float* __restrict__ in,
                                                 unsigned short* __restrict__ out, int n8) {
    const int stride = gridDim.x * 256;
    for (int i = blockIdx.x * 256 + threadIdx.x; i < n8; i += stride) {
        float4 a = reinterpret_cast<const float4*>(in)[(size_t)i * 2];
        float4 b = reinterpret_cast<const float4*>(in)[(size_t)i * 2 + 1];
        ushort8 u;
        u[0] = f2bf(a.x); u[1] = f2bf(a.y); u[2] = f2bf(a.z); u[3] = f2bf(a.w);
        u[4] = f2bf(b.x); u[5] = f2bf(b.y); u[6] = f2bf(b.z); u[7] = f2bf(b.w);
        reinterpret_cast<ushort8*>(out)[i] = u;
    }
}

// ---------------- q_proj[b][o] = sum_k query[b][k] * Ws[o][k] ----------------
__global__ __launch_bounds__(256) void k_qproj(const float* __restrict__ q,
                                               const float* __restrict__ Ws,
                                               float* __restrict__ qp) {
    const int b = blockIdx.y, oc = blockIdx.x, tid = threadIdx.x;
    __shared__ float ql[H_];
    for (int i = tid; i < H_; i += 256) ql[i] = q[b*H_ + i];
    __syncthreads();
    const int o = oc*256 + tid;
    const float4* w = reinterpret_cast<const float4*>(&Ws[(size_t)o * H_]);
    float acc = 0.f;
    #pragma unroll 4
    for (int k4 = 0; k4 < H_/4; ++k4) {
        float4 ww = w[k4];
        acc += ql[k4*4+0]*ww.x + ql[k4*4+1]*ww.y + ql[k4*4+2]*ww.z + ql[k4*4+3]*ww.w;
    }
    qp[b*H_ + o] = acc;
}

// ---------------- fused scores GEMM: r10 + fully-unrolled K-loop ----------------
// 128x128 tile, 4 waves, dbuf LDS, global_load_lds both operands, sync/K-step,
// ~4 blocks/CU. Slot-XOR involution swizzle (conflict-free reads, r2 coalescing).
// NEW vs r10: #pragma unroll on the 32 K-steps -> every staging/read address folds
// to an invariant VGPR base + instruction-immediate; per-iteration VALU ~0
// (r5 proved the fold: VALUBusy 65% -> 28%; r10 proved the occupancy; combined here).
__global__ __launch_bounds__(256) void k_scores_b(const unsigned short* __restrict__ encb,
                                                  const unsigned short* __restrict__ whb,
                                                  const float* __restrict__ qp,
                                                  const float* __restrict__ vw,
                                                  float* __restrict__ sp) {
    __shared__ __align__(1024) char As[2][8192];   // 8 subtiles x 1024B per buf
    __shared__ __align__(1024) char Bs[2][8192];
    __shared__ float sred[2][128];

    const int tid  = threadIdx.x;
    const int l    = tid & 63;
    const int w    = tid >> 6;       // wave 0..3
    const int wr   = w >> 1;         // row half (rows wr*64..+63)
    const int wc   = w & 1;          // col half
    const int fr   = l & 15;
    const int fh   = l >> 4;

    const int h  = blockIdx.x;                 // 8192 blocks
    const int L  = (h & 7) * 1024 + (h >> 3);  // XCD-group swizzle (bijective)
    const int bm = L >> 3;
    const int bn = L & 7;
    const int row0 = bm * 128;
    const int col0 = bn * 128;
    const int b = row0 >> 12;

    // ---- staging source (inverse-swizzled): slot t = tid&63 -> source slot
    //      sigma(t) = t ^ ((t>>3)&7): row sigma>>2, chunk sigma&3 ----
    const int t_    = tid & 63;
    const int sig   = t_ ^ ((t_ >> 3) & 7);
    const int s_sub = tid >> 6;                // subtile within instruction
    const int s_row = sig >> 2;
    const int s_ch  = (sig & 3) * 8;           // bf16 elements
    const unsigned short* gA0 = encb + (size_t)(row0 + s_sub*16 + s_row) * H_ + s_ch;
    const unsigned short* gA1 = gA0 + (size_t)64 * H_;   // subtiles 4..7
    const unsigned short* gB0 = whb  + (size_t)(col0 + s_sub*16 + s_row) * H_ + s_ch;
    const unsigned short* gB1 = gB0 + (size_t)64 * H_;

    // ---- read offset (swizzled): global slot g = 4*fr + fh -> LDS slot sigma(g) ----
    const int g_   = 4*fr + fh;
    const int rOff = (g_ ^ ((g_ >> 3) & 7)) * 16;

    f32x4 acc[4][4] = {};

    // prologue stage kt=0 into buf 0
    {
        char* la = &As[0][tid*16];
        char* lb = &Bs[0][tid*16];
        __builtin_amdgcn_global_load_lds((gbl_ptr_t)gA0, (lds_ptr_t)la,          16, 0, 0);
        __builtin_amdgcn_global_load_lds((gbl_ptr_t)gA1, (lds_ptr_t)(la + 4096), 16, 0, 0);
        __builtin_amdgcn_global_load_lds((gbl_ptr_t)gB0, (lds_ptr_t)lb,          16, 0, 0);
        __builtin_amdgcn_global_load_lds((gbl_ptr_t)gB1, (lds_ptr_t)(lb + 4096), 16, 0, 0);
    }
    __syncthreads();

    #pragma unroll
    for (int kt = 0; kt < 32; ++kt) {
        const int cur = kt & 1, nxt = cur ^ 1;
        if (kt < 31) {
            // kt+1 literal under unroll: global offset folds to imm, LDS base compile-time
            char* la = &As[nxt][tid*16];
            char* lb = &Bs[nxt][tid*16];
            __builtin_amdgcn_global_load_lds((gbl_ptr_t)(gA0 + (kt+1)*32), (lds_ptr_t)la,          16, 0, 0);
            __builtin_amdgcn_global_load_lds((gbl_ptr_t)(gA1 + (kt+1)*32), (lds_ptr_t)(la + 4096), 16, 0, 0);
            __builtin_amdgcn_global_load_lds((gbl_ptr_t)(gB0 + (kt+1)*32), (lds_ptr_t)lb,          16, 0, 0);
            __builtin_amdgcn_global_load_lds((gbl_ptr_t)(gB1 + (kt+1)*32), (lds_ptr_t)(lb + 4096), 16, 0, 0);
        }

        bf16x8 af[4], bfr[4];
        #pragma unroll
        for (int i = 0; i < 4; ++i) {
            af[i]  = *reinterpret_cast<const bf16x8*>(&As[cur][(wr*4 + i)*1024 + rOff]);
            bfr[i] = *reinterpret_cast<const bf16x8*>(&Bs[cur][(wc*4 + i)*1024 + rOff]);
        }
        #pragma unroll
        for (int i = 0; i < 4; ++i)
            #pragma unroll
            for (int j = 0; j < 4; ++j)
                acc[i][j] = __builtin_amdgcn_mfma_f32_16x16x32_bf16(af[i], bfr[j], acc[i][j], 0, 0, 0);

        __syncthreads();
    }

    // epilogue: s_partial[row] = sum_c v[c] * tanh(qp[b][c] + x[row][c])
    float vv[4], qq[4];
    #pragma unroll
    for (int j = 0; j < 4; ++j) {
        int c = col0 + wc*64 + j*16 + fr;
        vv[j] = vw[c];
        qq[j] = qp[b*H_ + c];
    }
    #pragma unroll
    for (int i = 0; i < 4; ++i) {
        #pragma unroll
        for (int r = 0; r < 4; ++r) {
            float s = 0.f;
            #pragma unroll
            for (int j = 0; j < 4; ++j)
                s += vv[j] * tanh_fast(qq[j] + acc[i][j][r]);
            s += __shfl_xor(s, 1, 64); s += __shfl_xor(s, 2, 64);
            s += __shfl_xor(s, 4, 64); s += __shfl_xor(s, 8, 64);
            if (fr == 0)
                sred[wc][wr*64 + i*16 + fh*4 + r] = s;
        }
    }
    __syncthreads();
    if (tid < 128)
        sp[(size_t)bn * M_ + row0 + tid] = sred[0][tid] + sred[1][tid];
}

// ---------------- fused scores GEMM, fp32 A in-flight (fallback, 128^2) ----------------
__global__ __launch_bounds__(256) void k_scores_f(const float* __restrict__ enc,
                                                  const unsigned short* __restrict__ whb,
                                                  const float* __restrict__ qp,
                                                  const float* __restrict__ vw,
                                                  float* __restrict__ sp) {
    __shared__ __align__(16) unsigned short As[2][128][32];
    __shared__ __align__(16) unsigned short Bs[2][128][32];
    __shared__ float sred[2][128];

    const int tid  = threadIdx.x;
    const int lane = tid & 63;
    const int wid  = tid >> 6;
    const int wr = wid >> 1, wc = wid & 1;
    const int fr = lane & 15;
    const int fk = (lane >> 4) * 8;

    const int h  = blockIdx.x;
    const int L  = (h & 7) * 1024 + (h >> 3);
    const int bm = L >> 3;
    const int bn = L & 7;
    const int row0 = bm * 128;
    const int col0 = bn * 128;
    const int b = row0 >> 12;

    const int ar = tid >> 3;
    const int ak = (tid & 7) * 4;
    const int bnr = tid >> 2;
    const int bkk = (tid & 3) * 8;

    float4 areg[4];
    auto loadA = [&](int kt) {
        #pragma unroll
        for (int p = 0; p < 4; ++p)
            areg[p] = *reinterpret_cast<const float4*>(
                &enc[(size_t)(row0 + p*32 + ar) * H_ + kt*32 + ak]);
    };
    auto writeA = [&](int buf) {
        #pragma unroll
        for (int p = 0; p < 4; ++p) {
            ushort4 u;
            u.x = f2bf(areg[p].x); u.y = f2bf(areg[p].y);
            u.z = f2bf(areg[p].z); u.w = f2bf(areg[p].w);
            *reinterpret_cast<ushort4*>(&As[buf][p*32 + ar][ak]) = u;
        }
    };
    auto stageB = [&](int buf, int kt) {
        const unsigned short* g0 = whb + (size_t)(col0 + bnr) * H_ + kt*32 + bkk;
        const unsigned short* g1 = g0 + (size_t)64 * H_;
        char* l0 = (char*)(&Bs[buf][0][0]) + tid*16;
        __builtin_amdgcn_global_load_lds((gbl_ptr_t)g0, (lds_ptr_t)l0,        16, 0, 0);
        __builtin_amdgcn_global_load_lds((gbl_ptr_t)g1, (lds_ptr_t)(l0+4096), 16, 0, 0);
    };

    f32x4 acc[4][4] = {};

    loadA(0);
    stageB(0, 0);
    writeA(0);
    __syncthreads();

    for (int kt = 0; kt < 32; ++kt) {
        const int cur = kt & 1, nxt = cur ^ 1;
        if (kt < 31) { stageB(nxt, kt + 1); loadA(kt + 1); }

        bf16x8 af[4], bfr[4];
        #pragma unroll
        for (int i = 0; i < 4; ++i) {
            af[i]  = *reinterpret_cast<const bf16x8*>(&As[cur][wr*64 + i*16 + fr][fk]);
            bfr[i] = *reinterpret_cast<const bf16x8*>(&Bs[cur][wc*64 + i*16 + fr][fk]);
        }
        #pragma unroll
        for (int i = 0; i < 4; ++i)
            #pragma unroll
            for (int j = 0; j < 4; ++j)
                acc[i][j] = __builtin_amdgcn_mfma_f32_16x16x32_bf16(af[i], bfr[j], acc[i][j], 0, 0, 0);

        if (kt < 31) writeA(nxt);
        __syncthreads();
    }

    float vv[4], qq[4];
    #pragma unroll
    for (int j = 0; j < 4; ++j) {
        int c = col0 + wc*64 + j*16 + fr;
        vv[j] = vw[c];
        qq[j] = qp[b*H_ + c];
    }
    #pragma unroll
    for (int i = 0; i < 4; ++i) {
        #pragma unroll
        for (int r = 0; r < 4; ++r) {
            float s = 0.f;
            #pragma unroll
            for (int j = 0; j < 4; ++j)
                s += vv[j] * tanh_fast(qq[j] + acc[i][j][r]);
            #pragma unroll
            for (int m = 1; m < 16; m <<= 1)
                s += __shfl_xor(s, m, 64);
            if (fr == 0)
                sred[wc][wr*64 + i*16 + (lane >> 4)*4 + r] = s;
        }
    }
    __syncthreads();
    if (tid < 128)
        sp[(size_t)bn * M_ + row0 + tid] = sred[0][tid] + sred[1][tid];
}

// ---------------- softmax over S per batch (P partial panels) ----------------
__global__ __launch_bounds__(256) void k_softmax(const float* __restrict__ sp,
                                                 float* __restrict__ attn, int P) {
    const int b = blockIdx.x, tid = threadIdx.x;
    __shared__ float red[4];
    float vals[16];
    float mx = -1e30f;
    #pragma unroll
    for (int i = 0; i < 16; ++i) {
        int s = i*256 + tid;
        float x = 0.f;
        for (int p = 0; p < P; ++p) x += sp[(size_t)p*M_ + b*S_ + s];
        vals[i] = x;
        mx = fmaxf(mx, x);
    }
    #pragma unroll
    for (int m = 1; m < 64; m <<= 1) mx = fmaxf(mx, __shfl_xor(mx, m, 64));
    if ((tid & 63) == 0) red[tid >> 6] = mx;
    __syncthreads();
    mx = fmaxf(fmaxf(red[0], red[1]), fmaxf(red[2], red[3]));
    float sum = 0.f;
    #pragma unroll
    for (int i = 0; i < 16; ++i) { vals[i] = __expf(vals[i] - mx); sum += vals[i]; }
    #pragma unroll
    for (int m = 1; m < 64; m <<= 1) sum += __shfl_xor(sum, m, 64);
    __syncthreads();
    if ((tid & 63) == 0) red[tid >> 6] = sum;
    __syncthreads();
    sum = red[0] + red[1] + red[2] + red[3];
    float inv = 1.f / sum;
    #pragma unroll
    for (int i = 0; i < 16; ++i) attn[b*S_ + i*256 + tid] = vals[i] * inv;
}

// ---------------- ctx partials, bf16 enc ----------------
__global__ __launch_bounds__(256) void k_ctx_b(const float* __restrict__ attn,
                                               const unsigned short* __restrict__ encb,
                                               float* __restrict__ ctxp) {
    const int sc = blockIdx.x;      // 0..15
    const int b  = blockIdx.y;
    const int hh = threadIdx.x * 4;
    float ax = 0.f, ay = 0.f, az = 0.f, aw = 0.f;
    const int s0 = sc * 256;
    #pragma unroll 4
    for (int s = s0; s < s0 + 256; ++s) {
        float a = attn[b*S_ + s];
        ushort4 e = *reinterpret_cast<const ushort4*>(&encb[((size_t)b*S_ + s) * H_ + hh]);
        ax += a*bf2f(e.x); ay += a*bf2f(e.y); az += a*bf2f(e.z); aw += a*bf2f(e.w);
    }
    float4 o; o.x = ax; o.y = ay; o.z = az; o.w = aw;
    *reinterpret_cast<float4*>(&ctxp[((size_t)sc*B_ + b) * H_ + hh]) = o;
}

// ---------------- ctx partials, fp32 enc (fallback) ----------------
__global__ __launch_bounds__(256) void k_ctx_f(const float* __restrict__ attn,
                                               const float* __restrict__ enc,
                                               float* __restrict__ ctxp) {
    const int sc = blockIdx.x;
    const int b  = blockIdx.y;
    const int hh = threadIdx.x * 4;
    float ax = 0.f, ay = 0.f, az = 0.f, aw = 0.f;
    const int s0 = sc * 256;
    #pragma unroll 4
    for (int s = s0; s < s0 + 256; ++s) {
        float a = attn[b*S_ + s];
        float4 e = *reinterpret_cast<const float4*>(&enc[((size_t)b*S_ + s) * H_ + hh]);
        ax += a*e.x; ay += a*e.y; az += a*e.z; aw += a*e.w;
    }
    float4 o; o.x = ax; o.y = ay; o.z = az; o.w = aw;
    *reinterpret_cast<float4*>(&ctxp[((size_t)sc*B_ + b) * H_ + hh]) = o;
}

// ---------------- out[b][o] = tanh(sum_k cat[b][k] * Wout[o][k]) ----------------
__global__ __launch_bounds__(256) void k_out(const float* __restrict__ ctxp,
                                             const float* __restrict__ q,
                                             const float* __restrict__ Wout,
                                             float* __restrict__ out) {
    const int oc = blockIdx.x, b = blockIdx.y, tid = threadIdx.x;
    __shared__ float cat[2*H_];
    for (int k = tid; k < H_; k += 256) {
        float s = 0.f;
        #pragma unroll
        for (int p = 0; p < 16; ++p) s += ctxp[((size_t)p*B_ + b) * H_ + k];
        cat[k] = s;
        cat[H_ + k] = q[b*H_ + k];
    }
    __syncthreads();
    const int o = oc*256 + tid;
    const float4* w = reinterpret_cast<const float4*>(&Wout[(size_t)o * 2*H_]);
    float acc = 0.f;
    #pragma unroll 4
    for (int k4 = 0; k4 < 2*H_/4; ++k4) {
        float4 ww = w[k4];
        acc += cat[k4*4+0]*ww.x + cat[k4*4+1]*ww.y + cat[k4*4+2]*ww.z + cat[k4*4+3]*ww.w;
    }
    out[b*H_ + o] = tanh_fast(acc);
}

extern "C" void kernel_launch(void* const* d_in, const int* in_sizes, int n_in,
                              void* d_out, int out_size, void* d_ws, size_t ws_size,
                              hipStream_t stream) {
    const float* query = (const float*)d_in[0];
    const float* enc   = (const float*)d_in[1];
    // d_in[2] = src_lengths (int64) — dead in the reference, faithfully unused
    const float* Ws    = (const float*)d_in[3];
    const float* Wh    = (const float*)d_in[4];
    const float* vw    = (const float*)d_in[5];
    const float* Wout  = (const float*)d_in[6];
    float* out = (float*)d_out;

    char* ws = (char*)d_ws;

    if (ws_size >= (266ull << 20)) {
        unsigned short* encb = (unsigned short*)ws;                        // 256 MiB
        unsigned short* whb  = (unsigned short*)(ws + (256ull << 20));     // 2 MiB
        float* sp   = (float*)(ws + (258ull << 20));                       // [8][M] 4 MiB
        float* attn = (float*)(ws + (262ull << 20));                       // 512 KiB
        float* qp   = (float*)(ws + (262ull << 20) + (512u << 10));        // 128 KiB
        float* ctxp = (float*)(ws + (263ull << 20));                       // 2 MiB

        k_cvt_enc <<<dim3(2048),    dim3(256), 0, stream>>>(enc, encb, M_*H_/8);
        k_cvt_bf16<<<dim3(1024),    dim3(256), 0, stream>>>(Wh, whb, H_*H_/4);
        k_qproj   <<<dim3(4, 32),   dim3(256), 0, stream>>>(query, Ws, qp);
        k_scores_b<<<dim3(8192),    dim3(256), 0, stream>>>(encb, whb, qp, vw, sp);
        k_softmax <<<dim3(32),      dim3(256), 0, stream>>>(sp, attn, 8);
        k_ctx_b   <<<dim3(16, 32),  dim3(256), 0, stream>>>(attn, encb, ctxp);
        k_out     <<<dim3(4, 32),   dim3(256), 0, stream>>>(ctxp, query, Wout, out);
    } else {
        unsigned short* whb = (unsigned short*)ws;
        float* sp   = (float*)(ws + (2u  << 20));
        float* attn = (float*)(ws + (6u  << 20));
        float* qp   = (float*)(ws + (6u  << 20) + (512u << 10));
        float* ctxp = (float*)(ws + (7u  << 20));

        k_cvt_bf16<<<dim3(1024),    dim3(256), 0, stream>>>(Wh, whb, H_*H_/4);
        k_qproj   <<<dim3(4, 32),   dim3(256), 0, stream>>>(query, Ws, qp);
        k_scores_f<<<dim3(8192),    dim3(256), 0, stream>>>(enc, whb, qp, vw, sp);
        k_softmax <<<dim3(32),      dim3(256), 0, stream>>>(sp, attn, 8);
        k_ctx_f   <<<dim3(16, 32),  dim3(256), 0, stream>>>(attn, enc, ctxp);
        k_out     <<<dim3(4, 32),   dim3(256), 0, stream>>>(ctxp, query, Wout, out);
    }
}